// Round 3
// baseline (302.620 us; speedup 1.0000x reference)
//
#include <hip/hip_runtime.h>

// SchNet forward, MI355X. B=8,A=256,N=255,NB=NF=128,NG=25,NI=3,CUTOFF=5.
// R3: wave-per-atom k_pairs (512 blocks = single batch, no main-loop barriers),
//     epilogue MLP as separate parallel kernel with transposed fp32 weights.

#define NATOM 2048   // B*A
#define NNBR  255

typedef __attribute__((ext_vector_type(8))) short bf16x8;  // 8 bf16 = 4 VGPR
typedef __attribute__((ext_vector_type(4))) float f32x4;

__device__ __forceinline__ unsigned short f2bf(float x){
  unsigned int u = __float_as_uint(x);
  u += 0x7fffu + ((u >> 16) & 1u);            // round-to-nearest-even
  return (unsigned short)(u >> 16);
}

// ssp(x) = softplus(x) - ln2 = ln(0.5*e^x + 0.5)
__device__ __forceinline__ float sspf(float x){
  return __logf(fmaf(0.5f, __expf(x), 0.5f));
}

// ---------- geometry + deterministic compaction of active (S!=0) neighbors
__global__ void k_prep(const float* __restrict__ pos, const int* __restrict__ nbr,
                       const float* __restrict__ mask,
                       float* __restrict__ r_c, float* __restrict__ S_c,
                       int* __restrict__ nb_c, int* __restrict__ nact_g){
  __shared__ int wcnt[4];
  const int n = threadIdx.x, atom = blockIdx.x, molBase = atom & ~255;
  const int wid = n >> 6, lane = n & 63;
  float r = 0.f, S = 0.f; int nb = 0;
  if (n < NNBR){
    nb = nbr[atom*NNBR + n];
    const float ax = pos[atom*3+0], ay = pos[atom*3+1], az = pos[atom*3+2];
    const int pi = (molBase + nb)*3;
    const float dx = pos[pi+0]-ax, dy = pos[pi+1]-ay, dz = pos[pi+2]-az;
    r = sqrtf(dx*dx + dy*dy + dz*dz + 1e-12f);
    const float m = mask[atom*NNBR + n];
    r *= m;
    const float C = (r < 5.0f) ? 0.5f*(__cosf(r*0.6283185307179586f)+1.0f) : 0.f;
    S = C * m;
  }
  r_c[atom*256 + n] = 0.f; S_c[atom*256 + n] = 0.f; nb_c[atom*256 + n] = 0;
  const unsigned long long b = __ballot(S != 0.f);
  const int rank = __popcll(b & ((1ull << lane) - 1ull));
  if (lane == 0) wcnt[wid] = __popcll(b);
  __syncthreads();
  int off = 0;
  for (int w = 0; w < 4; ++w) if (w < wid) off += wcnt[w];
  if (S != 0.f){
    const int slot = off + rank;
    r_c[atom*256 + slot] = r; S_c[atom*256 + slot] = S; nb_c[atom*256 + slot] = nb;
  }
  if (n == 0) nact_g[atom] = wcnt[0] + wcnt[1] + wcnt[2] + wcnt[3];
}

// ---- weights: fw1/fw2 -> MFMA B-frags (bf16); f2out/dense/in2f -> transposed f32
__global__ void k_prepw(const float* __restrict__ fw1, const float* __restrict__ fw2,
                        const float* __restrict__ f2w, const float* __restrict__ dw,
                        const float* __restrict__ in2f,
                        unsigned short* __restrict__ b1f, unsigned short* __restrict__ b2f,
                        float* __restrict__ wT){
  const int i = blockIdx.x, tid = threadIdx.x;
  const float* w1 = fw1 + i*25*128;
  const float* w2 = fw2 + i*128*128;
  unsigned short* o1 = b1f + i*8*64*8;
  unsigned short* o2 = b2f + i*32*64*8;
  for (int idx = tid; idx < 8*64; idx += 256){       // GEMM1 B: K=32 (25 padded)
    const int n = idx >> 6, l = idx & 63, khi = l >> 4, llo = l & 15;
    for (int j = 0; j < 8; ++j){
      const int g = khi*8 + j;
      o1[idx*8 + j] = f2bf((g < 25) ? w1[g*128 + n*16 + llo] : 0.f);
    }
  }
  for (int idx = tid; idx < 32*64; idx += 256){      // GEMM2 B: 4 K-steps x 8 N-tiles
    const int frag = idx >> 6, l = idx & 63;
    const int k0 = frag >> 3, n = frag & 7, khi = l >> 4, llo = l & 15;
    for (int j = 0; j < 8; ++j){
      const int k = k0*32 + khi*8 + j;
      o2[idx*8 + j] = f2bf(w2[k*128 + n*16 + llo]);
    }
  }
  // transposed fp32 copies: dst[t][d] = src[d][t]
  for (int m = 0; m < 3; ++m){
    const float* src = (m == 0 ? f2w : (m == 1 ? dw : in2f)) + i*16384;
    float* dst = wT + (i*3 + m)*16384;
    for (int idx = tid; idx < 16384; idx += 256){
      const int r = idx >> 7, c = idx & 127;
      dst[c*128 + r] = src[idx];
    }
  }
}

// ------------------------------------------ x = emb[Z]; y = x @ in2f_0
__global__ void k_init(const int* __restrict__ Z, const float* __restrict__ emb,
                       const float* __restrict__ in2fT,
                       float* __restrict__ x, float* __restrict__ y){
  __shared__ float xs[128];
  const int t = threadIdx.x, atom = blockIdx.x;
  const float v = emb[Z[atom]*128 + t];
  x[atom*128 + t] = v; xs[t] = v;
  __syncthreads();
  float acc = 0.f;
  const float4* w4 = (const float4*)(in2fT + t*128);
  #pragma unroll 8
  for (int d4 = 0; d4 < 32; ++d4){
    const float4 w = w4[d4];
    acc = fmaf(xs[d4*4+0], w.x, acc); acc = fmaf(xs[d4*4+1], w.y, acc);
    acc = fmaf(xs[d4*4+2], w.z, acc); acc = fmaf(xs[d4*4+3], w.w, acc);
  }
  y[atom*128 + t] = acc;
}

// ---- x += ssp(agg@f2out+b)@dense+b ; then y = x @ in2f_next (if given)
__global__ void k_mlp(const float* __restrict__ agg,
                      const float* __restrict__ f2outT, const float* __restrict__ b_f2out,
                      const float* __restrict__ denseT, const float* __restrict__ b_dense,
                      const float* __restrict__ in2fT_next,
                      float* __restrict__ x, float* __restrict__ y){
  __shared__ float aggL[128], v1[128], xs[128];
  const int t = threadIdx.x, atom = blockIdx.x;
  aggL[t] = agg[atom*128 + t];
  __syncthreads();
  float a = 0.f;
  {
    const float4* w4 = (const float4*)(f2outT + t*128);
    #pragma unroll 8
    for (int d4 = 0; d4 < 32; ++d4){
      const float4 w = w4[d4];
      a = fmaf(aggL[d4*4+0], w.x, a); a = fmaf(aggL[d4*4+1], w.y, a);
      a = fmaf(aggL[d4*4+2], w.z, a); a = fmaf(aggL[d4*4+3], w.w, a);
    }
  }
  v1[t] = sspf(a + b_f2out[t]);
  __syncthreads();
  float b = 0.f;
  {
    const float4* w4 = (const float4*)(denseT + t*128);
    #pragma unroll 8
    for (int d4 = 0; d4 < 32; ++d4){
      const float4 w = w4[d4];
      b = fmaf(v1[d4*4+0], w.x, b); b = fmaf(v1[d4*4+1], w.y, b);
      b = fmaf(v1[d4*4+2], w.z, b); b = fmaf(v1[d4*4+3], w.w, b);
    }
  }
  const float xn = x[atom*128 + t] + b + b_dense[t];
  x[atom*128 + t] = xn;
  if (in2fT_next){
    xs[t] = xn;
    __syncthreads();
    float yv = 0.f;
    const float4* w4 = (const float4*)(in2fT_next + t*128);
    #pragma unroll 8
    for (int d4 = 0; d4 < 32; ++d4){
      const float4 w = w4[d4];
      yv = fmaf(xs[d4*4+0], w.x, yv); yv = fmaf(xs[d4*4+1], w.y, yv);
      yv = fmaf(xs[d4*4+2], w.z, yv); yv = fmaf(xs[d4*4+3], w.w, yv);
    }
    y[atom*128 + t] = yv;
  }
}

// ---------------- wave-per-atom: filter net (MFMA) + cfconv aggregation
__global__ __launch_bounds__(256, 2) void k_pairs(
    const float* __restrict__ r_c, const float* __restrict__ S_c,
    const int* __restrict__ nb_c, const int* __restrict__ nact_g,
    const float* __restrict__ y,
    const unsigned short* __restrict__ b1f, const unsigned short* __restrict__ b2f,
    const float* __restrict__ fb1, const float* __restrict__ fb2,
    float* __restrict__ agg){
  // LDS: [0,32K) B2s (shared, read-only after barrier); [32K,48K) per-wave Hw 4KB
  __shared__ __align__(16) char smem[49152];
  unsigned short* B2s = (unsigned short*)smem;

  const int tid = threadIdx.x;
  const int wid = tid >> 6, lane = tid & 63, lhi = lane >> 4, llo = lane & 15;
  const int atom = blockIdx.x*4 + wid, molBase = atom & ~255;
  char* Hw = smem + 32768 + wid*4096;

  { // B2 fragments -> LDS (coalesced 32KB copy)
    const float4* src = (const float4*)b2f;
    float4* dst = (float4*)B2s;
    #pragma unroll
    for (int k = 0; k < 8; ++k) dst[k*256 + tid] = src[k*256 + tid];
  }
  bf16x8 B1[8];
  #pragma unroll
  for (int n = 0; n < 8; ++n) B1[n] = *(const bf16x8*)(b1f + (n*64 + lane)*8);
  float b1b[8], b2b[8];
  #pragma unroll
  for (int n = 0; n < 8; ++n){ b1b[n] = fb1[n*16 + llo]; b2b[n] = fb2[n*16 + llo]; }

  const int nact = nact_g[atom];
  const int ntiles = (nact + 15) >> 4;

  float aggp[8];
  #pragma unroll
  for (int n = 0; n < 8; ++n) aggp[n] = 0.f;

  const float STEP = 5.0f/24.0f;
  const float GC   = -11.52f;              // -0.5/STEP^2
  const f32x4 zero4 = {0.f,0.f,0.f,0.f};

  __syncthreads();                         // B2s ready; no barriers after this

  for (int t = 0; t < ntiles; ++t){
    const int row0 = t*16;
    // A1 fragment in-register: f[row0+llo][g=8*lhi+jj]
    const float r = r_c[atom*256 + row0 + llo];
    bf16x8 a1;
    #pragma unroll
    for (int jj = 0; jj < 8; ++jj){
      const int g = lhi*8 + jj;
      float v = 0.f;
      if (g < 25){ const float d = r - (float)g*STEP; v = __expf(GC*d*d); }
      a1[jj] = (short)f2bf(v);
    }
    // GEMM1: H(16x128) = f @ fw1
    f32x4 h[8];
    #pragma unroll
    for (int n = 0; n < 8; ++n)
      h[n] = __builtin_amdgcn_mfma_f32_16x16x32_bf16(a1, B1[n], zero4, 0, 0, 0);
    // ssp -> bf16 into wave-local swizzled LDS (transpose for GEMM2 A-frag)
    #pragma unroll
    for (int n = 0; n < 8; ++n)
      #pragma unroll
      for (int j = 0; j < 4; ++j){
        const int lrow = 4*lhi + j;
        const float hv = sspf(h[n][j] + b1b[n]);
        const int boff = (lrow*256 + (n*16 + llo)*2) ^ ((lrow & 7) << 4);
        *(unsigned short*)(Hw + boff) = f2bf(hv);
      }
    // GEMM2: W(16x128) = H @ fw2, K=128 in 4 steps
    f32x4 acc[8];
    #pragma unroll
    for (int n = 0; n < 8; ++n) acc[n] = zero4;
    #pragma unroll
    for (int k0 = 0; k0 < 4; ++k0){
      const int boff = (llo*256 + k0*64 + lhi*16) ^ ((llo & 7) << 4);
      const bf16x8 a2 = *(const bf16x8*)(Hw + boff);
      #pragma unroll
      for (int n = 0; n < 8; ++n){
        const bf16x8 b2v = *(const bf16x8*)(B2s + ((k0*8 + n)*64 + lane)*8);
        acc[n] = __builtin_amdgcn_mfma_f32_16x16x32_bf16(a2, b2v, acc[n], 0, 0, 0);
      }
    }
    // aggregate: agg[f] += (W+b2)*S * y[nbr]
    #pragma unroll
    for (int j = 0; j < 4; ++j){
      const int grow = row0 + 4*lhi + j;
      const float S = S_c[atom*256 + grow];
      const float* yrow = y + (molBase + nb_c[atom*256 + grow])*128;
      #pragma unroll
      for (int n = 0; n < 8; ++n)
        aggp[n] = fmaf((acc[n][j] + b2b[n]) * S, yrow[n*16 + llo], aggp[n]);
    }
  }

  // wave-local reduction across the 4 row-groups (lanes l, l^16, l^32, l^48)
  #pragma unroll
  for (int n = 0; n < 8; ++n){
    aggp[n] += __shfl_xor(aggp[n], 16);
    aggp[n] += __shfl_xor(aggp[n], 32);
  }
  if (lane < 16){
    #pragma unroll
    for (int n = 0; n < 8; ++n) agg[atom*128 + n*16 + lane] = aggp[n];
  }
}

// ---------------------------------------------------------------------------
extern "C" void kernel_launch(void* const* d_in, const int* in_sizes, int n_in,
                              void* d_out, int out_size, void* d_ws, size_t ws_size,
                              hipStream_t stream){
  const int*   Z    = (const int*)  d_in[0];
  const float* pos  = (const float*)d_in[1];
  const int*   nbr  = (const int*)  d_in[2];
  const float* mask = (const float*)d_in[3];
  const float* emb  = (const float*)d_in[4];
  const float* fw1  = (const float*)d_in[5];
  const float* fb1  = (const float*)d_in[6];
  const float* fw2  = (const float*)d_in[7];
  const float* fb2  = (const float*)d_in[8];
  const float* in2f = (const float*)d_in[9];
  const float* f2w  = (const float*)d_in[10];
  const float* f2b  = (const float*)d_in[11];
  const float* dw   = (const float*)d_in[12];
  const float* db   = (const float*)d_in[13];
  float* x = (float*)d_out;

  char* ws = (char*)d_ws;
  float* y    = (float*)ws;                               // 1MB
  float* agg  = (float*)(ws + 1*1024*1024);               // 1MB
  float* r_c  = (float*)(ws + 2*1024*1024);               // 2MB
  float* S_c  = (float*)(ws + 4*1024*1024);               // 2MB
  int*   nb_c = (int*)  (ws + 6*1024*1024);               // 2MB
  int*   nact = (int*)  (ws + 8*1024*1024);               // 8KB
  unsigned short* b1f = (unsigned short*)(ws + 8*1024*1024 + 16*1024);   // 24KB
  unsigned short* b2f = (unsigned short*)(ws + 8*1024*1024 + 64*1024);   // 96KB
  float* wT = (float*)(ws + 8*1024*1024 + 256*1024);      // 9 x 64KB

  k_prepw<<<3,     256, 0, stream>>>(fw1, fw2, f2w, dw, in2f, b1f, b2f, wT);
  k_prep <<<NATOM, 256, 0, stream>>>(pos, nbr, mask, r_c, S_c, nb_c, nact);
  k_init <<<NATOM, 128, 0, stream>>>(Z, emb, wT + 2*16384, x, y);
  for (int i = 0; i < 3; ++i){
    k_pairs<<<NATOM/4, 256, 0, stream>>>(r_c, S_c, nb_c, nact, y,
        b1f + i*8*64*8, b2f + i*32*64*8, fb1 + i*128, fb2 + i*128, agg);
    k_mlp  <<<NATOM, 128, 0, stream>>>(agg,
        wT + (i*3+0)*16384, f2b + i*128,
        wT + (i*3+1)*16384, db  + i*128,
        (i < 2) ? (wT + ((i+1)*3+2)*16384) : nullptr, x, y);
  }
}

// Round 4
// 223.822 us; speedup vs baseline: 1.3521x; 1.3521x over previous
//
#include <hip/hip_runtime.h>

// SchNet forward, MI355X. B=8,A=256,N=255,NB=NF=128,NG=25,NI=3,CUTOFF=5.
// R4: parallel coalesced weight-prep; coalesced-broadcast GEMV epilogues;
//     k_pairs with 2 waves/atom -> 4 waves/SIMD, single batch, no wT.

#define NATOM 2048   // B*A
#define NNBR  255

typedef __attribute__((ext_vector_type(8))) short bf16x8;  // 8 bf16 = 4 VGPR
typedef __attribute__((ext_vector_type(4))) float f32x4;

__device__ __forceinline__ unsigned short f2bf(float x){
  unsigned int u = __float_as_uint(x);
  u += 0x7fffu + ((u >> 16) & 1u);            // round-to-nearest-even
  return (unsigned short)(u >> 16);
}

// ssp(x) = softplus(x) - ln2 = ln(0.5*e^x + 0.5)
__device__ __forceinline__ float sspf(float x){
  return __logf(fmaf(0.5f, __expf(x), 0.5f));
}

// ---------- geometry + deterministic compaction of active (S!=0) neighbors
__global__ void k_prep(const float* __restrict__ pos, const int* __restrict__ nbr,
                       const float* __restrict__ mask,
                       float* __restrict__ r_c, float* __restrict__ S_c,
                       int* __restrict__ nb_c, int* __restrict__ nact_g){
  __shared__ int wcnt[4];
  const int n = threadIdx.x, atom = blockIdx.x, molBase = atom & ~255;
  const int wid = n >> 6, lane = n & 63;
  float r = 0.f, S = 0.f; int nb = 0;
  if (n < NNBR){
    nb = nbr[atom*NNBR + n];
    const float ax = pos[atom*3+0], ay = pos[atom*3+1], az = pos[atom*3+2];
    const int pi = (molBase + nb)*3;
    const float dx = pos[pi+0]-ax, dy = pos[pi+1]-ay, dz = pos[pi+2]-az;
    r = sqrtf(dx*dx + dy*dy + dz*dz + 1e-12f);
    const float m = mask[atom*NNBR + n];
    r *= m;
    const float C = (r < 5.0f) ? 0.5f*(__cosf(r*0.6283185307179586f)+1.0f) : 0.f;
    S = C * m;
  }
  r_c[atom*256 + n] = 0.f; S_c[atom*256 + n] = 0.f; nb_c[atom*256 + n] = 0;
  const unsigned long long b = __ballot(S != 0.f);
  const int rank = __popcll(b & ((1ull << lane) - 1ull));
  if (lane == 0) wcnt[wid] = __popcll(b);
  __syncthreads();
  int off = 0;
  for (int w = 0; w < 4; ++w) if (w < wid) off += wcnt[w];
  if (S != 0.f){
    const int slot = off + rank;
    r_c[atom*256 + slot] = r; S_c[atom*256 + slot] = S; nb_c[atom*256 + slot] = nb;
  }
  if (n == 0) nact_g[atom] = wcnt[0] + wcnt[1] + wcnt[2] + wcnt[3];
}

// ---- fw1/fw2 -> MFMA B-frags (bf16), parallel + coalesced.
// grid = 3 iters x 10 parts; part 0-1: b1f (512 entries), part 2-9: b2f (2048).
__global__ void k_prepw(const float* __restrict__ fw1, const float* __restrict__ fw2,
                        unsigned short* __restrict__ b1f, unsigned short* __restrict__ b2f){
  const int i = blockIdx.x / 10, part = blockIdx.x % 10, tid = threadIdx.x;
  if (part < 2){
    const int e = part*256 + tid;                    // entry in [0,512)
    const float* w1 = fw1 + i*25*128;
    unsigned short* o1 = b1f + i*512*8;
    const int n = e >> 6, l = e & 63, khi = l >> 4, llo = l & 15;
    unsigned short v[8];
    #pragma unroll
    for (int j = 0; j < 8; ++j){
      const int g = khi*8 + j;
      v[j] = f2bf((g < 25) ? w1[g*128 + n*16 + llo] : 0.f);
    }
    *(float4*)(o1 + e*8) = *(float4*)v;
  } else {
    const int e = (part - 2)*256 + tid;              // entry in [0,2048)
    const float* w2 = fw2 + i*128*128;
    unsigned short* o2 = b2f + i*2048*8;
    const int frag = e >> 6, l = e & 63;
    const int k0 = frag >> 3, n = frag & 7, khi = l >> 4, llo = l & 15;
    unsigned short v[8];
    #pragma unroll
    for (int j = 0; j < 8; ++j){
      const int k = k0*32 + khi*8 + j;
      v[j] = f2bf(w2[k*128 + n*16 + llo]);
    }
    *(float4*)(o2 + e*8) = *(float4*)v;
  }
}

// ------------------------------------------ x = emb[Z]; y = x @ in2f_0
__global__ void k_init(const int* __restrict__ Z, const float* __restrict__ emb,
                       const float* __restrict__ in2f0,
                       float* __restrict__ x, float* __restrict__ y){
  __shared__ float xs[128];
  const int t = threadIdx.x, atom = blockIdx.x;
  const float v = emb[Z[atom]*128 + t];
  x[atom*128 + t] = v; xs[t] = v;
  __syncthreads();
  float acc[8] = {0.f,0.f,0.f,0.f,0.f,0.f,0.f,0.f};
  #pragma unroll 4
  for (int d0 = 0; d0 < 128; d0 += 8)
    #pragma unroll
    for (int u = 0; u < 8; ++u)
      acc[u] = fmaf(xs[d0+u], in2f0[(d0+u)*128 + t], acc[u]);
  y[atom*128 + t] = ((acc[0]+acc[1])+(acc[2]+acc[3]))+((acc[4]+acc[5])+(acc[6]+acc[7]));
}

// ---- x += ssp(agg@f2out+b)@dense+b ; then y = x @ in2f_next (if given)
// All weight reads coalesced (lane = output col), activations LDS-broadcast.
__global__ void k_mlp(const float* __restrict__ agg,
                      const float* __restrict__ f2w, const float* __restrict__ f2b,
                      const float* __restrict__ dw, const float* __restrict__ db,
                      const float* __restrict__ in2f_next,
                      float* __restrict__ x, float* __restrict__ y){
  __shared__ float aggL[128], v1[128], xs[128];
  const int t = threadIdx.x, atom = blockIdx.x;
  aggL[t] = agg[atom*128 + t];
  __syncthreads();
  float a[8] = {0.f,0.f,0.f,0.f,0.f,0.f,0.f,0.f};
  #pragma unroll 4
  for (int d0 = 0; d0 < 128; d0 += 8)
    #pragma unroll
    for (int u = 0; u < 8; ++u)
      a[u] = fmaf(aggL[d0+u], f2w[(d0+u)*128 + t], a[u]);
  v1[t] = sspf(((a[0]+a[1])+(a[2]+a[3]))+((a[4]+a[5])+(a[6]+a[7])) + f2b[t]);
  __syncthreads();
  float b[8] = {0.f,0.f,0.f,0.f,0.f,0.f,0.f,0.f};
  #pragma unroll 4
  for (int d0 = 0; d0 < 128; d0 += 8)
    #pragma unroll
    for (int u = 0; u < 8; ++u)
      b[u] = fmaf(v1[d0+u], dw[(d0+u)*128 + t], b[u]);
  const float xn = x[atom*128 + t] +
      (((b[0]+b[1])+(b[2]+b[3]))+((b[4]+b[5])+(b[6]+b[7]))) + db[t];
  x[atom*128 + t] = xn;
  if (in2f_next){
    xs[t] = xn;
    __syncthreads();
    float yv[8] = {0.f,0.f,0.f,0.f,0.f,0.f,0.f,0.f};
    #pragma unroll 4
    for (int d0 = 0; d0 < 128; d0 += 8)
      #pragma unroll
      for (int u = 0; u < 8; ++u)
        yv[u] = fmaf(xs[d0+u], in2f_next[(d0+u)*128 + t], yv[u]);
    y[atom*128 + t] = ((yv[0]+yv[1])+(yv[2]+yv[3]))+((yv[4]+yv[5])+(yv[6]+yv[7]));
  }
}

// ------ filter net (MFMA) + cfconv agg: 8 waves, 4 atoms/block, 2 waves/atom
__global__ __launch_bounds__(512, 4) void k_pairs(
    const float* __restrict__ r_c, const float* __restrict__ S_c,
    const int* __restrict__ nb_c, const int* __restrict__ nact_g,
    const float* __restrict__ y,
    const unsigned short* __restrict__ b1f, const unsigned short* __restrict__ b2f,
    const float* __restrict__ fb1, const float* __restrict__ fb2,
    float* __restrict__ agg){
  // LDS 64KB -> 2 blocks/CU (16 waves/CU = 4/SIMD):
  //  [0,32K)   B2s : 32 GEMM2 B-frags x 64 lanes x 16B (shared, read-only)
  //  [32K,64K) Hw  : per-wave 16x128 bf16 swizzled buffer (4KB/wave);
  //                  reused per-wave as red[128] f32 for the final reduce
  __shared__ __align__(16) char smem[65536];
  unsigned short* B2s = (unsigned short*)smem;

  const int tid = threadIdx.x;
  const int wid = tid >> 6, lane = tid & 63, lhi = lane >> 4, llo = lane & 15;
  const int sub = wid >> 2, a = wid & 3;            // 2 waves per atom
  const int atom = blockIdx.x*4 + a, molBase = atom & ~255;
  char* Hw = smem + 32768 + wid*4096;

  { // B2 fragments -> LDS (coalesced 32KB copy, 512 threads x 4 float4)
    const float4* src = (const float4*)b2f;
    float4* dst = (float4*)B2s;
    #pragma unroll
    for (int k = 0; k < 4; ++k) dst[k*512 + tid] = src[k*512 + tid];
  }
  bf16x8 B1[8];
  #pragma unroll
  for (int n = 0; n < 8; ++n) B1[n] = *(const bf16x8*)(b1f + (n*64 + lane)*8);
  float b1b[8], b2b[8];
  #pragma unroll
  for (int n = 0; n < 8; ++n){ b1b[n] = fb1[n*16 + llo]; b2b[n] = fb2[n*16 + llo]; }

  const int nact = nact_g[atom];
  const int ntiles = (nact + 15) >> 4;

  float aggp[8];
  #pragma unroll
  for (int n = 0; n < 8; ++n) aggp[n] = 0.f;

  const float STEP = 5.0f/24.0f;
  const float GC   = -11.52f;              // -0.5/STEP^2
  const f32x4 zero4 = {0.f,0.f,0.f,0.f};

  __syncthreads();                         // B2s ready

  for (int t = sub; t < ntiles; t += 2){
    const int row0 = t*16;
    // A1 fragment in-register: f[row0+llo][g=8*lhi+jj]
    const float r = r_c[atom*256 + row0 + llo];
    bf16x8 a1;
    #pragma unroll
    for (int jj = 0; jj < 8; ++jj){
      const int g = lhi*8 + jj;
      float v = 0.f;
      if (g < 25){ const float d = r - (float)g*STEP; v = __expf(GC*d*d); }
      a1[jj] = (short)f2bf(v);
    }
    // GEMM1: H(16x128) = f @ fw1
    f32x4 h[8];
    #pragma unroll
    for (int n = 0; n < 8; ++n)
      h[n] = __builtin_amdgcn_mfma_f32_16x16x32_bf16(a1, B1[n], zero4, 0, 0, 0);
    // ssp -> bf16 into wave-local swizzled LDS (transpose for GEMM2 A-frag)
    #pragma unroll
    for (int n = 0; n < 8; ++n)
      #pragma unroll
      for (int j = 0; j < 4; ++j){
        const int lrow = 4*lhi + j;
        const float hv = sspf(h[n][j] + b1b[n]);
        const int boff = (lrow*256 + (n*16 + llo)*2) ^ ((lrow & 7) << 4);
        *(unsigned short*)(Hw + boff) = f2bf(hv);
      }
    // GEMM2: W(16x128) = H @ fw2, K=128 in 4 steps
    f32x4 acc[8];
    #pragma unroll
    for (int n = 0; n < 8; ++n) acc[n] = zero4;
    #pragma unroll
    for (int k0 = 0; k0 < 4; ++k0){
      const int boff = (llo*256 + k0*64 + lhi*16) ^ ((llo & 7) << 4);
      const bf16x8 a2 = *(const bf16x8*)(Hw + boff);
      #pragma unroll
      for (int n = 0; n < 8; ++n){
        const bf16x8 b2v = *(const bf16x8*)(B2s + ((k0*8 + n)*64 + lane)*8);
        acc[n] = __builtin_amdgcn_mfma_f32_16x16x32_bf16(a2, b2v, acc[n], 0, 0, 0);
      }
    }
    // aggregate: agg[f] += (W+b2)*S * y[nbr]
    #pragma unroll
    for (int j = 0; j < 4; ++j){
      const int grow = row0 + 4*lhi + j;
      const float S = S_c[atom*256 + grow];
      const float* yrow = y + (molBase + nb_c[atom*256 + grow])*128;
      #pragma unroll
      for (int n = 0; n < 8; ++n)
        aggp[n] = fmaf((acc[n][j] + b2b[n]) * S, yrow[n*16 + llo], aggp[n]);
    }
  }

  // wave-local reduction across the 4 row-groups
  #pragma unroll
  for (int n = 0; n < 8; ++n){
    aggp[n] += __shfl_xor(aggp[n], 16);
    aggp[n] += __shfl_xor(aggp[n], 32);
  }
  // cross-wave (sub 0 + sub 1) via LDS
  float* red = (float*)Hw;
  if (lane < 16){
    #pragma unroll
    for (int n = 0; n < 8; ++n) red[n*16 + lane] = aggp[n];
  }
  __syncthreads();
  if (sub == 0 && lane < 16){
    const float* red1 = (const float*)(smem + 32768 + (wid + 4)*4096);
    #pragma unroll
    for (int n = 0; n < 8; ++n)
      agg[atom*128 + n*16 + lane] = red[n*16 + lane] + red1[n*16 + lane];
  }
}

// ---------------------------------------------------------------------------
extern "C" void kernel_launch(void* const* d_in, const int* in_sizes, int n_in,
                              void* d_out, int out_size, void* d_ws, size_t ws_size,
                              hipStream_t stream){
  const int*   Z    = (const int*)  d_in[0];
  const float* pos  = (const float*)d_in[1];
  const int*   nbr  = (const int*)  d_in[2];
  const float* mask = (const float*)d_in[3];
  const float* emb  = (const float*)d_in[4];
  const float* fw1  = (const float*)d_in[5];
  const float* fb1  = (const float*)d_in[6];
  const float* fw2  = (const float*)d_in[7];
  const float* fb2  = (const float*)d_in[8];
  const float* in2f = (const float*)d_in[9];
  const float* f2w  = (const float*)d_in[10];
  const float* f2b  = (const float*)d_in[11];
  const float* dw   = (const float*)d_in[12];
  const float* db   = (const float*)d_in[13];
  float* x = (float*)d_out;

  char* ws = (char*)d_ws;
  float* y    = (float*)ws;                               // 1MB
  float* agg  = (float*)(ws + 1*1024*1024);               // 1MB
  float* r_c  = (float*)(ws + 2*1024*1024);               // 2MB
  float* S_c  = (float*)(ws + 4*1024*1024);               // 2MB
  int*   nb_c = (int*)  (ws + 6*1024*1024);               // 2MB
  int*   nact = (int*)  (ws + 8*1024*1024);               // 8KB
  unsigned short* b1f = (unsigned short*)(ws + 8*1024*1024 + 16*1024);   // 24KB
  unsigned short* b2f = (unsigned short*)(ws + 8*1024*1024 + 64*1024);   // 96KB

  k_prepw<<<30,    256, 0, stream>>>(fw1, fw2, b1f, b2f);
  k_prep <<<NATOM, 256, 0, stream>>>(pos, nbr, mask, r_c, S_c, nb_c, nact);
  k_init <<<NATOM, 128, 0, stream>>>(Z, emb, in2f, x, y);
  for (int i = 0; i < 3; ++i){
    k_pairs<<<NATOM/4, 512, 0, stream>>>(r_c, S_c, nb_c, nact, y,
        b1f + i*512*8, b2f + i*2048*8, fb1 + i*128, fb2 + i*128, agg);
    k_mlp  <<<NATOM, 128, 0, stream>>>(agg,
        f2w + i*16384, f2b + i*128, dw + i*16384, db + i*128,
        (i < 2) ? (in2f + (i+1)*16384) : nullptr, x, y);
  }
}